// Round 2
// baseline (205.963 us; speedup 1.0000x reference)
//
#include <hip/hip_runtime.h>

typedef short s16x8 __attribute__((ext_vector_type(8)));
typedef float f32x4 __attribute__((ext_vector_type(4)));

__device__ inline unsigned short bf16_rn(float f) {
  unsigned int u = __float_as_uint(f);
  return (unsigned short)((u + 0x7FFFu + ((u >> 16) & 1u)) >> 16);
}
__device__ inline float bf16f(unsigned short h) {
  return __uint_as_float(((unsigned int)h) << 16);
}

// async global->LDS DMA, 16 B per lane; LDS dest = wave-uniform base + lane*16
typedef __attribute__((address_space(3))) unsigned int lds_u32_t;
typedef __attribute__((address_space(1))) const unsigned int g_u32_t;
__device__ __forceinline__ void gload_lds16(const void* g, void* l) {
  __builtin_amdgcn_global_load_lds((g_u32_t*)g, (lds_u32_t*)l, 16, 0, 0);
}

// ---------------------------------------------------------------------------
// Kernel 1: codebook -> 32-code-tiled XOR-swizzled hi/lo bf16 image + norms.
// Tile = 32 codes = 16 KB: [hi 32x128 ushort | lo 32x128 ushort]. Row r
// stores 8-dim chunk c at chunk slot c ^ (r & 15) (conflict-free ds_read).
// ---------------------------------------------------------------------------
__global__ __launch_bounds__(64) void vq_convert_cb(const float* __restrict__ cb,
                                                    unsigned short* __restrict__ cbimg,
                                                    float* __restrict__ cbn) {
  int k = blockIdx.x * 64 + threadIdx.x;  // 0..1023
  int tile = k >> 5, r = k & 31, sm = r & 15;
  const float* row = cb + (size_t)k * 128;
  float nrm = 0.f;
#pragma unroll
  for (int c = 0; c < 16; ++c) {
    float4 a = *(const float4*)(row + c * 8);
    float4 b = *(const float4*)(row + c * 8 + 4);
    float v[8] = {a.x, a.y, a.z, a.w, b.x, b.y, b.z, b.w};
    unsigned int hw[4], lw[4];
#pragma unroll
    for (int i = 0; i < 4; ++i) {
      unsigned short h0 = bf16_rn(v[2 * i]), h1 = bf16_rn(v[2 * i + 1]);
      float r0 = v[2 * i] - bf16f(h0), r1 = v[2 * i + 1] - bf16f(h1);
      unsigned short l0 = bf16_rn(r0), l1 = bf16_rn(r1);
      hw[i] = (unsigned)h0 | ((unsigned)h1 << 16);
      lw[i] = (unsigned)l0 | ((unsigned)l1 << 16);
      nrm += v[2 * i] * v[2 * i] + v[2 * i + 1] * v[2 * i + 1];
    }
    int cs = c ^ sm;
    unsigned short* dh = cbimg + (size_t)tile * 8192 + r * 128 + cs * 8;
    *(uint4*)dh = make_uint4(hw[0], hw[1], hw[2], hw[3]);
    *(uint4*)(dh + 4096) = make_uint4(lw[0], lw[1], lw[2], lw[3]);
  }
  cbn[k] = nrm;
}

// ---------------------------------------------------------------------------
// Kernel 2: fused main. 512 blocks x 512 thr (8 waves). LDS ~37.4 KB
// -> 4 blocks/CU = 32 waves/CU = 8 waves/SIMD (VGPR=64 bucket, enforced).
// Wave owns 16 tokens. 32 codebook tiles (32 codes each) stream through
// dbuf LDS via async global_load_lds; 3-pass split-bf16 MFMA with setprio;
// min/max-based exact top-2; two-pass exact fp32 rescore epilogue;
// block-local loss reduction (no memset/atomics).
// ---------------------------------------------------------------------------
__global__ __launch_bounds__(512, 8) void vq_main(
    const float* __restrict__ xg, const float* __restrict__ cb,
    const unsigned short* __restrict__ cbimg, const float* __restrict__ cbn,
    float* __restrict__ xq, float* __restrict__ loss) {
  __shared__ __attribute__((aligned(16))) unsigned short sB[2][8192];  // 32 KB
  __shared__ float sNorm[1024];
  __shared__ int sKK[128];
  __shared__ float sLoss[8];
  const int tid = threadIdx.x;
  const int wave = tid >> 6, lane = tid & 63;
  const int i0 = lane & 15, q = lane >> 4;
  const int tokW = blockIdx.x * 128 + wave * 16;

  // ---- stage codebook norms into LDS (4 KB, 512 thr x float2) ----
  *(float2*)&sNorm[tid * 2] = *(const float2*)(cbn + tid * 2);

  // ---- load own 16 tokens, split fp32 -> bf16 hi + bf16 lo in-register ----
  s16x8 ahi[4], alo[4];
#pragma unroll
  for (int kf = 0; kf < 4; ++kf) {
    const float* p = xg + (size_t)(tokW + i0) * 128 + kf * 32 + q * 8;
    float4 a = *(const float4*)p, b = *(const float4*)(p + 4);
    float v[8] = {a.x, a.y, a.z, a.w, b.x, b.y, b.z, b.w};
    s16x8 h, l;
#pragma unroll
    for (int j = 0; j < 8; ++j) {
      unsigned short hh = bf16_rn(v[j]);
      float rr = v[j] - bf16f(hh);
      h[j] = (short)hh;
      l[j] = (short)bf16_rn(rr);
    }
    ahi[kf] = h;
    alo[kf] = l;
  }

  int boff[4][2];  // LDS ushort offsets for B-frag reads (XOR de-swizzle)
#pragma unroll
  for (int ks = 0; ks < 4; ++ks)
#pragma unroll
    for (int c = 0; c < 2; ++c)
      boff[ks][c] = (c * 16 + i0) * 128 + (((ks * 4 + q) ^ i0) * 8);

  // ---- async stage tile 0 (2 x 1KB slices per wave, 8 waves = 16 KB) ----
  const char* gbase = (const char*)cbimg;
  const int so = wave * 2048 + lane * 16;  // per-lane global offset in tile
  const int su = wave * 2048;              // wave-uniform LDS offset
  {
    const char* g = gbase + so;
    char* l = (char*)&sB[0][0] + su;
    gload_lds16(g, l);
    gload_lds16(g + 1024, l + 1024);
  }

  float d1[4], d2[4];
  int k1[4], k2[4];
#pragma unroll
  for (int g = 0; g < 4; ++g) {
    d1[g] = 3.4e38f; d2[g] = 3.4e38f; k1[g] = 0; k2[g] = 0;
  }
  __syncthreads();  // drains vmcnt -> tile 0 resident

  for (int t = 0; t < 32; ++t) {
    const int cur = t & 1;
    if (t < 31) {  // async prefetch of tile t+1 into the other buffer
      const char* g = gbase + (t + 1) * 16384 + so;
      char* l = (char*)&sB[1 - cur][0] + su;
      gload_lds16(g, l);
      gload_lds16(g + 1024, l + 1024);
    }
    f32x4 acc[2];
    acc[0] = (f32x4){0.f, 0.f, 0.f, 0.f};
    acc[1] = (f32x4){0.f, 0.f, 0.f, 0.f};

#pragma unroll
    for (int ks = 0; ks < 4; ++ks) {
      s16x8 bhi[2], blo[2];
#pragma unroll
      for (int c = 0; c < 2; ++c) {
        bhi[c] = *(const s16x8*)&sB[cur][boff[ks][c]];
        blo[c] = *(const s16x8*)&sB[cur][boff[ks][c] + 4096];
      }
      __builtin_amdgcn_s_setprio(1);
#pragma unroll
      for (int c = 0; c < 2; ++c)
        acc[c] = __builtin_amdgcn_mfma_f32_16x16x32_bf16(ahi[ks], bhi[c], acc[c], 0, 0, 0);
#pragma unroll
      for (int c = 0; c < 2; ++c)
        acc[c] = __builtin_amdgcn_mfma_f32_16x16x32_bf16(ahi[ks], blo[c], acc[c], 0, 0, 0);
#pragma unroll
      for (int c = 0; c < 2; ++c)
        acc[c] = __builtin_amdgcn_mfma_f32_16x16x32_bf16(alo[ks], bhi[c], acc[c], 0, 0, 0);
      __builtin_amdgcn_s_setprio(0);
    }
    // ---- exact top-2 update (min/max form); strict < keeps first-min ----
#pragma unroll
    for (int c = 0; c < 2; ++c) {
      int kc = t * 32 + c * 16 + i0;
      float cn = sNorm[kc];
#pragma unroll
      for (int g = 0; g < 4; ++g) {
        float dd = fmaf(-2.f, acc[c][g], cn);
        bool w = dd < d1[g];
        float ld = fmaxf(dd, d1[g]);   // loser of {dd, d1}
        int lk = w ? k1[g] : kc;       // loser's key (tie -> new/larger kc)
        d1[g] = fminf(dd, d1[g]);
        k1[g] = w ? kc : k1[g];
        bool w2 = ld < d2[g];
        d2[g] = fminf(ld, d2[g]);
        k2[g] = w2 ? lk : k2[g];
      }
    }
    __syncthreads();  // waves done reading cur; prefetch into 1-cur drained
  }

  // ---- butterfly merge of top-2 across the 16 i0-lanes (lex d,k) ----
#pragma unroll
  for (int off = 1; off < 16; off <<= 1) {
#pragma unroll
    for (int g = 0; g < 4; ++g) {
      float od1 = __shfl_xor(d1[g], off);
      int ok1 = __shfl_xor(k1[g], off);
      float od2 = __shfl_xor(d2[g], off);
      int ok2 = __shfl_xor(k2[g], off);
      bool t1 = (od1 < d1[g]) || (od1 == d1[g] && ok1 < k1[g]);
      float w1d = t1 ? od1 : d1[g];
      int w1k = t1 ? ok1 : k1[g];
      float l1d = t1 ? d1[g] : od1;  // loser of the firsts
      int l1k = t1 ? k1[g] : ok1;
      float c2d = t1 ? od2 : d2[g];  // winner's own second
      int c2k = t1 ? ok2 : k2[g];
      bool t2 = (l1d < c2d) || (l1d == c2d && l1k < c2k);
      d1[g] = w1d; k1[g] = w1k;
      d2[g] = t2 ? l1d : c2d;
      k2[g] = t2 ? l1k : c2k;
    }
  }

  if (i0 == 0) {
#pragma unroll
    for (int g = 0; g < 4; ++g)
      sKK[wave * 16 + q * 4 + g] = k1[g] | (k2[g] << 10);
  }
  __syncthreads();

  // ---- two-pass epilogue: exact fp32 rescore (streaming, no row buffers),
  //      then winner re-read (L2-hot) + coalesced xq store; loss reduce ----
  float lacc = 0.f;
  {
    int kk = sKK[wave * 16 + i0];
    int ka = kk & 1023, kb = (kk >> 10) & 1023;
    size_t token = (size_t)tokW + i0;
    float s1 = 0.f, s2 = 0.f;
#pragma unroll
    for (int kf = 0; kf < 4; ++kf) {
      const float* xp = xg + token * 128 + kf * 32 + q * 8;
      float4 xa = *(const float4*)xp, xb = *(const float4*)(xp + 4);
      const float* p1 = cb + (size_t)ka * 128 + kf * 32 + q * 8;
      float4 ua = *(const float4*)p1, ub = *(const float4*)(p1 + 4);
      const float* p2 = cb + (size_t)kb * 128 + kf * 32 + q * 8;
      float4 va = *(const float4*)p2, vb = *(const float4*)(p2 + 4);
      float xv[8] = {xa.x, xa.y, xa.z, xa.w, xb.x, xb.y, xb.z, xb.w};
      float e1[8] = {ua.x, ua.y, ua.z, ua.w, ub.x, ub.y, ub.z, ub.w};
      float e2[8] = {va.x, va.y, va.z, va.w, vb.x, vb.y, vb.z, vb.w};
#pragma unroll
      for (int j = 0; j < 8; ++j) {
        float f1 = xv[j] - e1[j];
        float f2 = xv[j] - e2[j];
        s1 = fmaf(f1, f1, s1);
        s2 = fmaf(f2, f2, s2);
      }
    }
    s1 += __shfl_xor(s1, 16); s1 += __shfl_xor(s1, 32);
    s2 += __shfl_xor(s2, 16); s2 += __shfl_xor(s2, 32);
    bool tk = (s2 < s1) || (s2 == s1 && kb < ka);
    int kw = tk ? kb : ka;
    float dwin = tk ? s2 : s1;
#pragma unroll
    for (int kf = 0; kf < 4; ++kf) {
      const float* pw = cb + (size_t)kw * 128 + kf * 32 + q * 8;
      float4 wa = *(const float4*)pw, wb = *(const float4*)(pw + 4);
      float* op = xq + token * 128 + kf * 32 + q * 8;
      *(float4*)op = wa;
      *(float4*)(op + 4) = wb;
    }
    if (q == 0) lacc += dwin;
  }
#pragma unroll
  for (int off = 1; off < 64; off <<= 1) lacc += __shfl_xor(lacc, off);
  if (lane == 0) sLoss[wave] = lacc;
  __syncthreads();
  // block fully owns loss[blockIdx.x] (128 tokens = one (b,s) slice):
  // plain store, no memset, no atomics.
  if (tid == 0) {
    float s = 0.f;
#pragma unroll
    for (int w = 0; w < 8; ++w) s += sLoss[w];
    loss[blockIdx.x] = s * (1.25f / 16384.f);
  }
}

// ---------------------------------------------------------------------------
extern "C" void kernel_launch(void* const* d_in, const int* in_sizes, int n_in,
                              void* d_out, int out_size, void* d_ws, size_t ws_size,
                              hipStream_t stream) {
  const float* x = (const float*)d_in[0];   // [8,64,128,128] fp32
  const float* cb = (const float*)d_in[1];  // [1024,128] fp32
  float* out = (float*)d_out;
  float* xq = out;
  float* loss = out + (size_t)8 * 64 * 128 * 128;  // 512 floats

  // ws: cbimg 512 KB | cbn 4 KB
  unsigned short* cbimg = (unsigned short*)d_ws;
  float* cbn = (float*)(cbimg + (size_t)1024 * 128 * 2);

  vq_convert_cb<<<16, 64, 0, stream>>>(cb, cbimg, cbn);
  vq_main<<<512, 512, 0, stream>>>(x, cb, cbimg, cbn, xq, loss);
}

// Round 3
// 146.889 us; speedup vs baseline: 1.4022x; 1.4022x over previous
//
#include <hip/hip_runtime.h>

typedef short s16x8 __attribute__((ext_vector_type(8)));
typedef float f32x4 __attribute__((ext_vector_type(4)));

__device__ inline unsigned short bf16_rn(float f) {
  unsigned int u = __float_as_uint(f);
  return (unsigned short)((u + 0x7FFFu + ((u >> 16) & 1u)) >> 16);
}
__device__ inline float bf16f(unsigned short h) {
  return __uint_as_float(((unsigned int)h) << 16);
}

// async global->LDS DMA, 16 B per lane; LDS dest = wave-uniform base + lane*16
typedef __attribute__((address_space(3))) unsigned int lds_u32_t;
typedef __attribute__((address_space(1))) const unsigned int g_u32_t;
__device__ __forceinline__ void gload_lds16(const void* g, void* l) {
  __builtin_amdgcn_global_load_lds((g_u32_t*)g, (lds_u32_t*)l, 16, 0, 0);
}

// ---------------------------------------------------------------------------
// Kernel 1: codebook -> 32-code-tiled XOR-swizzled hi/lo bf16 image + norms.
// Tile = 32 codes = 16 KB: [hi 32x128 ushort | lo 32x128 ushort]. Row r
// stores 8-dim chunk c at chunk slot c ^ (r & 15) (conflict-free ds_read).
// ---------------------------------------------------------------------------
__global__ __launch_bounds__(64) void vq_convert_cb(const float* __restrict__ cb,
                                                    unsigned short* __restrict__ cbimg,
                                                    float* __restrict__ cbn) {
  int k = blockIdx.x * 64 + threadIdx.x;  // 0..1023
  int tile = k >> 5, r = k & 31, sm = r & 15;
  const float* row = cb + (size_t)k * 128;
  float nrm = 0.f;
#pragma unroll
  for (int c = 0; c < 16; ++c) {
    float4 a = *(const float4*)(row + c * 8);
    float4 b = *(const float4*)(row + c * 8 + 4);
    float v[8] = {a.x, a.y, a.z, a.w, b.x, b.y, b.z, b.w};
    unsigned int hw[4], lw[4];
#pragma unroll
    for (int i = 0; i < 4; ++i) {
      unsigned short h0 = bf16_rn(v[2 * i]), h1 = bf16_rn(v[2 * i + 1]);
      float r0 = v[2 * i] - bf16f(h0), r1 = v[2 * i + 1] - bf16f(h1);
      unsigned short l0 = bf16_rn(r0), l1 = bf16_rn(r1);
      hw[i] = (unsigned)h0 | ((unsigned)h1 << 16);
      lw[i] = (unsigned)l0 | ((unsigned)l1 << 16);
      nrm += v[2 * i] * v[2 * i] + v[2 * i + 1] * v[2 * i + 1];
    }
    int cs = c ^ sm;
    unsigned short* dh = cbimg + (size_t)tile * 8192 + r * 128 + cs * 8;
    *(uint4*)dh = make_uint4(hw[0], hw[1], hw[2], hw[3]);
    *(uint4*)(dh + 4096) = make_uint4(lw[0], lw[1], lw[2], lw[3]);
  }
  cbn[k] = nrm;
}

// ---------------------------------------------------------------------------
// Kernel 2: fused main. 512 blocks x 512 thr (8 waves, launch_bounds(512,4)
// -> 128-reg budget, NO spills; R2's (512,8) spilled in-loop). Wave owns 16
// tokens. 32 codebook tiles stream through TRIPLE-buffered LDS (48 KB) with
// depth-2 async prefetch + counted s_waitcnt vmcnt(2) + raw s_barrier — the
// per-tile vmcnt(0) drain of __syncthreads was the dominant stall (T3/T4).
// 3-pass split-bf16 MFMA with setprio; min/max exact top-2; two-pass exact
// fp32 rescore epilogue; block-local loss (no memset/atomics).
// ---------------------------------------------------------------------------
__global__ __launch_bounds__(512, 4) void vq_main(
    const float* __restrict__ xg, const float* __restrict__ cb,
    const unsigned short* __restrict__ cbimg, const float* __restrict__ cbn,
    float* __restrict__ xq, float* __restrict__ loss) {
  __shared__ __attribute__((aligned(16))) unsigned short sB[3][8192];  // 48 KB
  __shared__ float sNorm[1024];
  __shared__ int sKK[128];
  __shared__ float sLoss[8];
  const int tid = threadIdx.x;
  const int wave = tid >> 6, lane = tid & 63;
  const int i0 = lane & 15, q = lane >> 4;
  const int tokW = blockIdx.x * 128 + wave * 16;

  // ---- stage codebook norms into LDS (4 KB, 512 thr x float2) ----
  *(float2*)&sNorm[tid * 2] = *(const float2*)(cbn + tid * 2);

  // ---- load own 16 tokens, split fp32 -> bf16 hi + bf16 lo in-register ----
  s16x8 ahi[4], alo[4];
#pragma unroll
  for (int kf = 0; kf < 4; ++kf) {
    const float* p = xg + (size_t)(tokW + i0) * 128 + kf * 32 + q * 8;
    float4 a = *(const float4*)p, b = *(const float4*)(p + 4);
    float v[8] = {a.x, a.y, a.z, a.w, b.x, b.y, b.z, b.w};
    s16x8 h, l;
#pragma unroll
    for (int j = 0; j < 8; ++j) {
      unsigned short hh = bf16_rn(v[j]);
      float rr = v[j] - bf16f(hh);
      h[j] = (short)hh;
      l[j] = (short)bf16_rn(rr);
    }
    ahi[kf] = h;
    alo[kf] = l;
  }

  int boff[4][2];  // LDS ushort offsets for B-frag reads (XOR de-swizzle)
#pragma unroll
  for (int ks = 0; ks < 4; ++ks)
#pragma unroll
    for (int c = 0; c < 2; ++c)
      boff[ks][c] = (c * 16 + i0) * 128 + (((ks * 4 + q) ^ i0) * 8);

  // ---- prologue: async stage tile 0 -> buf0, tile 1 -> buf1 ----
  // per wave: 2 KB per tile = 2 x gload16 per lane
  const char* gbase = (const char*)cbimg;
  const int so = wave * 2048 + lane * 16;  // per-lane global offset in tile
  const int su = wave * 2048;              // wave-uniform LDS offset
  {
    gload_lds16(gbase + so, (char*)&sB[0][0] + su);
    gload_lds16(gbase + so + 1024, (char*)&sB[0][0] + su + 1024);
    gload_lds16(gbase + 16384 + so, (char*)&sB[1][0] + su);
    gload_lds16(gbase + 16384 + so + 1024, (char*)&sB[1][0] + su + 1024);
  }

  float d1[4], d2[4];
  int k1[4], k2[4];
#pragma unroll
  for (int g = 0; g < 4; ++g) {
    d1[g] = 3.4e38f; d2[g] = 3.4e38f; k1[g] = 0; k2[g] = 0;
  }
  // own tile-0 loads landed (vmcnt: tile-1's 2 remain) + norm ds_writes done,
  // then barrier -> collectively tile 0 resident & sNorm visible.
  asm volatile("s_waitcnt vmcnt(2) lgkmcnt(0)" ::: "memory");
  __builtin_amdgcn_s_barrier();

  int cur = 0;
  for (int t = 0; t < 32; ++t) {
    if (t + 2 < 32) {  // depth-2 prefetch: tile t+2 -> buf[(t+2)%3]
      int nb = cur + 2;
      nb = (nb >= 3) ? nb - 3 : nb;
      const char* g = gbase + (t + 2) * 16384 + so;
      char* l = (char*)&sB[nb][0] + su;
      gload_lds16(g, l);
      gload_lds16(g + 1024, l + 1024);
    }
    f32x4 acc[2];
    acc[0] = (f32x4){0.f, 0.f, 0.f, 0.f};
    acc[1] = (f32x4){0.f, 0.f, 0.f, 0.f};

#pragma unroll
    for (int ks = 0; ks < 4; ++ks) {
      s16x8 bhi[2], blo[2];
#pragma unroll
      for (int c = 0; c < 2; ++c) {
        bhi[c] = *(const s16x8*)&sB[cur][boff[ks][c]];
        blo[c] = *(const s16x8*)&sB[cur][boff[ks][c] + 4096];
      }
      __builtin_amdgcn_s_setprio(1);
#pragma unroll
      for (int c = 0; c < 2; ++c)
        acc[c] = __builtin_amdgcn_mfma_f32_16x16x32_bf16(ahi[ks], bhi[c], acc[c], 0, 0, 0);
#pragma unroll
      for (int c = 0; c < 2; ++c)
        acc[c] = __builtin_amdgcn_mfma_f32_16x16x32_bf16(ahi[ks], blo[c], acc[c], 0, 0, 0);
#pragma unroll
      for (int c = 0; c < 2; ++c)
        acc[c] = __builtin_amdgcn_mfma_f32_16x16x32_bf16(alo[ks], bhi[c], acc[c], 0, 0, 0);
      __builtin_amdgcn_s_setprio(0);
    }
    // ---- exact top-2 update (min/max form); strict < keeps first-min ----
#pragma unroll
    for (int c = 0; c < 2; ++c) {
      int kc = t * 32 + c * 16 + i0;
      float cn = sNorm[kc];
#pragma unroll
      for (int g = 0; g < 4; ++g) {
        float dd = fmaf(-2.f, acc[c][g], cn);
        bool w = dd < d1[g];
        float ld = fmaxf(dd, d1[g]);   // loser of {dd, d1}
        int lk = w ? k1[g] : kc;       // loser's key (tie -> new/larger kc)
        d1[g] = fminf(dd, d1[g]);
        k1[g] = w ? kc : k1[g];
        bool w2 = ld < d2[g];
        d2[g] = fminf(ld, d2[g]);
        k2[g] = w2 ? lk : k2[g];
      }
    }
    // ---- counted wait (tile t+1's loads, issued 2 phases ago) + pure sync.
    // Reads of buf[cur] are complete (consumed by MFMAs above), so after the
    // barrier the next iteration may safely overwrite buf[cur] via prefetch.
    if (t < 31) {
      if (t < 30) {
        asm volatile("s_waitcnt vmcnt(2)" ::: "memory");
      } else {
        asm volatile("s_waitcnt vmcnt(0)" ::: "memory");
      }
      __builtin_amdgcn_s_barrier();
    }
    cur = (cur == 2) ? 0 : cur + 1;
  }

  // ---- butterfly merge of top-2 across the 16 i0-lanes (lex d,k) ----
#pragma unroll
  for (int off = 1; off < 16; off <<= 1) {
#pragma unroll
    for (int g = 0; g < 4; ++g) {
      float od1 = __shfl_xor(d1[g], off);
      int ok1 = __shfl_xor(k1[g], off);
      float od2 = __shfl_xor(d2[g], off);
      int ok2 = __shfl_xor(k2[g], off);
      bool t1 = (od1 < d1[g]) || (od1 == d1[g] && ok1 < k1[g]);
      float w1d = t1 ? od1 : d1[g];
      int w1k = t1 ? ok1 : k1[g];
      float l1d = t1 ? d1[g] : od1;  // loser of the firsts
      int l1k = t1 ? k1[g] : ok1;
      float c2d = t1 ? od2 : d2[g];  // winner's own second
      int c2k = t1 ? ok2 : k2[g];
      bool t2 = (l1d < c2d) || (l1d == c2d && l1k < c2k);
      d1[g] = w1d; k1[g] = w1k;
      d2[g] = t2 ? l1d : c2d;
      k2[g] = t2 ? l1k : c2k;
    }
  }

  if (i0 == 0) {
#pragma unroll
    for (int g = 0; g < 4; ++g)
      sKK[wave * 16 + q * 4 + g] = k1[g] | (k2[g] << 10);
  }
  __syncthreads();

  // ---- two-pass epilogue: exact fp32 rescore (streaming, no row buffers),
  //      then winner re-read (L2-hot) + coalesced xq store; loss reduce ----
  float lacc = 0.f;
  {
    int kk = sKK[wave * 16 + i0];
    int ka = kk & 1023, kb = (kk >> 10) & 1023;
    size_t token = (size_t)tokW + i0;
    float s1 = 0.f, s2 = 0.f;
#pragma unroll
    for (int kf = 0; kf < 4; ++kf) {
      const float* xp = xg + token * 128 + kf * 32 + q * 8;
      float4 xa = *(const float4*)xp, xb = *(const float4*)(xp + 4);
      const float* p1 = cb + (size_t)ka * 128 + kf * 32 + q * 8;
      float4 ua = *(const float4*)p1, ub = *(const float4*)(p1 + 4);
      const float* p2 = cb + (size_t)kb * 128 + kf * 32 + q * 8;
      float4 va = *(const float4*)p2, vb = *(const float4*)(p2 + 4);
      float xv[8] = {xa.x, xa.y, xa.z, xa.w, xb.x, xb.y, xb.z, xb.w};
      float e1[8] = {ua.x, ua.y, ua.z, ua.w, ub.x, ub.y, ub.z, ub.w};
      float e2[8] = {va.x, va.y, va.z, va.w, vb.x, vb.y, vb.z, vb.w};
#pragma unroll
      for (int j = 0; j < 8; ++j) {
        float f1 = xv[j] - e1[j];
        float f2 = xv[j] - e2[j];
        s1 = fmaf(f1, f1, s1);
        s2 = fmaf(f2, f2, s2);
      }
    }
    s1 += __shfl_xor(s1, 16); s1 += __shfl_xor(s1, 32);
    s2 += __shfl_xor(s2, 16); s2 += __shfl_xor(s2, 32);
    bool tk = (s2 < s1) || (s2 == s1 && kb < ka);
    int kw = tk ? kb : ka;
    float dwin = tk ? s2 : s1;
#pragma unroll
    for (int kf = 0; kf < 4; ++kf) {
      const float* pw = cb + (size_t)kw * 128 + kf * 32 + q * 8;
      float4 wa = *(const float4*)pw, wb = *(const float4*)(pw + 4);
      float* op = xq + token * 128 + kf * 32 + q * 8;
      *(float4*)op = wa;
      *(float4*)(op + 4) = wb;
    }
    if (q == 0) lacc += dwin;
  }
#pragma unroll
  for (int off = 1; off < 64; off <<= 1) lacc += __shfl_xor(lacc, off);
  if (lane == 0) sLoss[wave] = lacc;
  __syncthreads();
  // block fully owns loss[blockIdx.x] (128 tokens = one (b,s) slice):
  // plain store, no memset, no atomics.
  if (tid == 0) {
    float s = 0.f;
#pragma unroll
    for (int w = 0; w < 8; ++w) s += sLoss[w];
    loss[blockIdx.x] = s * (1.25f / 16384.f);
  }
}

// ---------------------------------------------------------------------------
extern "C" void kernel_launch(void* const* d_in, const int* in_sizes, int n_in,
                              void* d_out, int out_size, void* d_ws, size_t ws_size,
                              hipStream_t stream) {
  const float* x = (const float*)d_in[0];   // [8,64,128,128] fp32
  const float* cb = (const float*)d_in[1];  // [1024,128] fp32
  float* out = (float*)d_out;
  float* xq = out;
  float* loss = out + (size_t)8 * 64 * 128 * 128;  // 512 floats

  // ws: cbimg 512 KB | cbn 4 KB
  unsigned short* cbimg = (unsigned short*)d_ws;
  float* cbn = (float*)(cbimg + (size_t)1024 * 128 * 2);

  vq_convert_cb<<<16, 64, 0, stream>>>(cb, cbimg, cbn);
  vq_main<<<512, 512, 0, stream>>>(x, cb, cbimg, cbn, xq, loss);
}